// Round 15
// baseline (94.467 us; speedup 1.0000x reference)
//
#include <hip/hip_runtime.h>

// X: (8, 2048, 256) fp32; W1: (64,8); b1: (64); W2: (2,64); b2: (2)
// patches: p = 0..510, l = 4p..4p+7 ; out: (8, 511, 256, 2) fp32
#define L_DIM 2048
#define C_DIM 256
#define P_CNT 511
#define H_DIM 64

typedef float v2f __attribute__((ext_vector_type(2)));
static __device__ __forceinline__ v2f splat2(float s) { return (v2f){s, s}; }

// Packed tanh-form gelu via native exp2:
//   z = t*(k1 + k2*t^2), k1=-1.5957691216*log2e, k2=-0.0713548162*log2e
//   gelu(t) = t * rcp(1 + 2^z).  Inf-safe at both tails.
__device__ __forceinline__ v2f pk_gelu(v2f t) {
    v2f t2 = t * t;
    v2f z  = t * __builtin_elementwise_fma(t2, splat2(-0.10294324f),
                                           splat2(-2.3022038f));
    v2f e;
    e.x = __builtin_amdgcn_exp2f(z.x);
    e.y = __builtin_amdgcn_exp2f(z.y);
    v2f den = e + splat2(1.0f);
    v2f r;
    r.x = __builtin_amdgcn_rcpf(den.x);
    r.y = __builtin_amdgcn_rcpf(den.y);
    return t * r;
}

// thread = (b, channel, 4 patches as two <2 x float>-packed pairs)
// R15: the per-h-iteration weight fetch (11 s_load dwords + waits) is a FIXED
// cost all lockstep waves pay together (R11: TLP-halving neutral; R5->R7:
// marginal instrs price at issue rate). Amortize it: 2x compute per iteration.
// threads = 8 * 256 * 128 = 262144 = 1024 blocks * 256 -> 4 waves/SIMD (enough).
__global__ __launch_bounds__(256, 4) void offset_predictor_kernel(
    const float* __restrict__ X,
    const float* __restrict__ W1,
    const float* __restrict__ b1,
    const float* __restrict__ W2,
    const float* __restrict__ b2,
    float* __restrict__ out)
{
    const int tid   = blockIdx.x * 256 + threadIdx.x;
    const int c     = tid & 255;            // consecutive threads -> consecutive channels
    const int ptile = (tid >> 8) & 127;
    const int b     = tid >> 15;
    const int p0    = ptile * 4;

    // pvA[j] = (X[4p0+j],   X[4p0+4+j])  -> patches p0, p0+1
    // pvB[j] = (X[4p0+8+j], X[4p0+12+j]) -> patches p0+2, p0+3
    const float* xb = X + (size_t)b * (L_DIM * C_DIM) + c;
    v2f pvA[8], pvB[8];
#pragma unroll
    for (int j = 0; j < 8; ++j) {
        int a0 = 4 * p0 + j;                 // <= 2043: always valid
        int a1 = a0 + 4;                     // <= 2047: always valid
        int b0 = a0 + 8;                     // <= 2047 only if p0+2 <= 510 (always)
        int b1_ = a0 + 12;
        if (b1_ > L_DIM - 1) b1_ = L_DIM - 1;  // ptile=127's invalid patch 511 only
        pvA[j].x = xb[(size_t)a0 * C_DIM];
        pvA[j].y = xb[(size_t)a1 * C_DIM];
        pvB[j].x = xb[(size_t)b0 * C_DIM];
        pvB[j].y = xb[(size_t)b1_ * C_DIM];
    }

    const float bo0 = b2[0], bo1 = b2[1];
    v2f accA0 = splat2(bo0);                // o0 @ (p0,   p0+1)
    v2f accB0 = splat2(bo1);                // o1 @ (p0,   p0+1)
    v2f accA1 = splat2(bo0);                // o0 @ (p0+2, p0+3)
    v2f accB1 = splat2(bo1);                // o1 @ (p0+2, p0+3)

#pragma unroll 4
    for (int h = 0; h < H_DIM; ++h) {
        const float4 wa = *(const float4*)(W1 + h * 8);      // w1[h][0..3]
        const float4 wb = *(const float4*)(W1 + h * 8 + 4);  // w1[h][4..7]
        const float b1h = b1[h];
        const float w2a = W2[h];             // W2[0][h]
        const float w2b = W2[H_DIM + h];     // W2[1][h]

        v2f t0 = splat2(b1h);                // patches (p0, p0+1)
        v2f t1 = splat2(b1h);                // patches (p0+2, p0+3)
        t0 = __builtin_elementwise_fma(pvA[0], splat2(wa.x), t0);
        t1 = __builtin_elementwise_fma(pvB[0], splat2(wa.x), t1);
        t0 = __builtin_elementwise_fma(pvA[1], splat2(wa.y), t0);
        t1 = __builtin_elementwise_fma(pvB[1], splat2(wa.y), t1);
        t0 = __builtin_elementwise_fma(pvA[2], splat2(wa.z), t0);
        t1 = __builtin_elementwise_fma(pvB[2], splat2(wa.z), t1);
        t0 = __builtin_elementwise_fma(pvA[3], splat2(wa.w), t0);
        t1 = __builtin_elementwise_fma(pvB[3], splat2(wa.w), t1);
        t0 = __builtin_elementwise_fma(pvA[4], splat2(wb.x), t0);
        t1 = __builtin_elementwise_fma(pvB[4], splat2(wb.x), t1);
        t0 = __builtin_elementwise_fma(pvA[5], splat2(wb.y), t0);
        t1 = __builtin_elementwise_fma(pvB[5], splat2(wb.y), t1);
        t0 = __builtin_elementwise_fma(pvA[6], splat2(wb.z), t0);
        t1 = __builtin_elementwise_fma(pvB[6], splat2(wb.z), t1);
        t0 = __builtin_elementwise_fma(pvA[7], splat2(wb.w), t0);
        t1 = __builtin_elementwise_fma(pvB[7], splat2(wb.w), t1);

        const v2f g0 = pk_gelu(t0);
        const v2f g1 = pk_gelu(t1);

        accA0 = __builtin_elementwise_fma(g0, splat2(w2a), accA0);
        accB0 = __builtin_elementwise_fma(g0, splat2(w2b), accB0);
        accA1 = __builtin_elementwise_fma(g1, splat2(w2a), accA1);
        accB1 = __builtin_elementwise_fma(g1, splat2(w2b), accB1);
    }

    // out[((b*511 + p)*256 + c)*2 + o] : contiguous float2 per thread, coalesced across c
    float* ob = out + ((size_t)(b * P_CNT) * C_DIM + c) * 2;
    *(float2*)(ob + (size_t)(p0 + 0) * (C_DIM * 2)) = make_float2(accA0.x, accB0.x);
    *(float2*)(ob + (size_t)(p0 + 1) * (C_DIM * 2)) = make_float2(accA0.y, accB0.y);
    *(float2*)(ob + (size_t)(p0 + 2) * (C_DIM * 2)) = make_float2(accA1.x, accB1.x);
    if (p0 + 3 < P_CNT)
        *(float2*)(ob + (size_t)(p0 + 3) * (C_DIM * 2)) = make_float2(accA1.y, accB1.y);
}

extern "C" void kernel_launch(void* const* d_in, const int* in_sizes, int n_in,
                              void* d_out, int out_size, void* d_ws, size_t ws_size,
                              hipStream_t stream) {
    const float* X  = (const float*)d_in[0];
    const float* W1 = (const float*)d_in[1];
    const float* b1 = (const float*)d_in[2];
    const float* W2 = (const float*)d_in[3];
    const float* b2 = (const float*)d_in[4];
    float* out = (float*)d_out;

    offset_predictor_kernel<<<1024, 256, 0, stream>>>(X, W1, b1, W2, b2, out);
}